// Round 14
// baseline (118.235 us; speedup 1.0000x reference)
//
#include <hip/hip_runtime.h>
#include <hip/hip_bf16.h>
#include <stdint.h>

typedef __attribute__((ext_vector_type(4))) float f32x4;
typedef __attribute__((ext_vector_type(8))) short bf16x8;

#define NCH  128
#define NREL 8

__device__ __forceinline__ unsigned short f2bf(float f) {
    unsigned u = __builtin_bit_cast(unsigned, f);
    u += 0x7fffu + ((u >> 16) & 1u);          // RNE to bf16
    return (unsigned short)(u >> 16);
}

__device__ __forceinline__ bool mask_used(const unsigned char* um, int stride, int s) {
    if (stride == 1) return um[s] != 0;
    if (stride == 4) return ((const int*)um)[s] != 0;
    return ((const long long*)um)[s] != 0;
}

// ---------------------------------------------------------------------------
// K1 (512 blocks x 256): pure Wb convert, 1 element/thread.
// Block 0 detects used_mask element width -> cn[1].
// ---------------------------------------------------------------------------
__global__ __launch_bounds__(256)
void k_prep(const float* __restrict__ W, unsigned short* __restrict__ Wb,
            int* __restrict__ cn, const unsigned char* __restrict__ um_raw) {
    const int t = threadIdx.x;
    const int o = blockIdx.x * 256 + t;
    {
        const int kk  = o & 31;
        const int col = (o >> 5) & (NCH - 1);
        const int kt  = o >> 12;
        Wb[o] = f2bf(W[(kt * 32 + kk) * NCH + col]);
    }
    if (blockIdx.x == 0) {
        __shared__ unsigned sA, sB;
        if (t == 0) { sA = 0; sB = 0; }
        __syncthreads();
        unsigned a = 0, b = 0;
        #pragma unroll 4
        for (int p = t; p < 1024; p += 256) {
            const unsigned v = um_raw[p];
            if ((p & 3) != 0) a |= v;   // bool kept 1B -> data off 4-align
            if ((p & 7) == 4) b |= v;   // int32 -> data at 4 mod 8
        }
        if (a) atomicOr(&sA, 1u);
        if (b) atomicOr(&sB, 1u);
        __syncthreads();
        if (t == 0) cn[1] = sA ? 1 : (sB ? 4 : 8);
    }
}

// ---------------------------------------------------------------------------
// K2 (2048 blocks x 512): window w = blockIdx>>1 owns nodes [w*64, w*64+64).
// Role by parity (interleaved so every CU holds a mix from t=0):
//   blockIdx&1==0 -> MAIN: ballot non-cached -> groups of 16 through the
//     proven pipeline (16 gathers in flight -> select-accumulate -> swizzled
//     LDS -> MFMA vs Wb -> LDS-staged contiguous 512B stores).
//   blockIdx&1==1 -> COPY: ballot cached -> 16 half-waves x 4 rounds copy
//     history rows to out (nontemporal).
// Self-classifying: no glist, no tickets, no memset, 2 dispatches total.
// Cross-block overlap of stream-bound copy and latency-bound gather (R12
// mechanism); R13 showed intra-block serialization kills it.
// ---------------------------------------------------------------------------
__global__ __launch_bounds__(512, 2)
void k_fused(const float* __restrict__ x, const unsigned short* __restrict__ Wb,
             const int* __restrict__ ptr, const int* __restrict__ idx,
             const int* __restrict__ et, const unsigned char* __restrict__ um,
             const int* __restrict__ cn, const float* __restrict__ hb,
             const int* __restrict__ hm, const int* __restrict__ hs,
             float* __restrict__ out, int num_node) {
    __shared__ __align__(16) char As[16 * NREL * NCH * 2];   // 32 KB, XOR-swizzled
    __shared__ int   lst[64];
    __shared__ int   cnt_s;
    __shared__ int   nidg[16];
    __shared__ float invdeg[16];

    const int t    = threadIdx.x;
    const int role = blockIdx.x & 1;        // 0 = main, 1 = copy
    const int n0   = (blockIdx.x >> 1) * 64;

    if (t < 64) {                                  // wave 0 classifies
        const int n = n0 + t;
        const bool valid  = n < num_node;
        const bool cached = valid && (hs[0] > 0) && (hm[n] != -1);
        const bool want   = role ? cached : (valid && !cached);
        const unsigned long long m = __ballot(want);
        if (want) lst[__popcll(m & ((1ull << t) - 1))] = n;
        if (t == 0) cnt_s = __popcll(m);
    }
    __syncthreads();
    const int cnt = cnt_s;
    const int hw    = t >> 5;       // half-wave id 0..15
    const int l     = t & 31;       // lane in half-wave; owns channels 4l..4l+3
    const int lbase = t & 32;       // half-wave base within its wave

    if (role) {                                    // ---- copy role ----
        int   node[4];
        f32x4 v[4];
        #pragma unroll 4
        for (int j = 0; j < 4; ++j) {
            const int i = hw + j * 16;
            node[j] = (i < cnt) ? lst[i] : -1;
            if (node[j] >= 0)
                v[j] = *(const f32x4*)(hb + (long)node[j] * NCH + l * 4);
        }
        #pragma unroll 4
        for (int j = 0; j < 4; ++j) {
            if (node[j] >= 0)
                __builtin_nontemporal_store(v[j],
                    (f32x4*)(out + (long)node[j] * NCH + l * 4));
        }
        return;
    }

    // ---- main role: groups of 16 non-cached nodes (avg ~10.7 -> 1 group) ----
    const int mstride = cn[1];
    const int nGroups = (cnt + 15) >> 4;
    for (int g = 0; g < nGroups; ++g) {
        if (t < 16) {
            const int i = g * 16 + t;
            nidg[t]   = (i < cnt) ? lst[i] : -1;
            invdeg[t] = 0.0f;
        }
        __syncthreads();

        const int n = nidg[hw];
        if (n >= 0) {
            const int p0 = ptr[n], p1 = ptr[n + 1];
            const int deg = p1 - p0;
            if (l == 0) invdeg[hw] = (deg > 0) ? 1.0f / (float)deg : 0.0f;
            // lanes 0..15 of the half-wave fetch edge meta, pack (rel<<24)|src
            int myPk = NREL << 24;
            if (l < 16 && (p0 + l) < p1) {
                const int e  = p0 + l;
                const int s  = idx[e];
                const int tt = et[e];
                myPk = s | (((mask_used(um, mstride, s) && tt >= 0 && tt < NREL)
                             ? tt : NREL) << 24);
            }
            // all 16 row-gathers in flight before any consumption
            int   pk[16];
            f32x4 xv[16];
            #pragma unroll 16
            for (int e = 0; e < 16; ++e) {
                pk[e] = __shfl(myPk, lbase + e, 64);
                xv[e] = *(const f32x4*)(x + (long)(pk[e] & 0xFFFFFF) * NCH + l * 4);
            }
            float acc[NREL][4];
            #pragma unroll
            for (int q = 0; q < NREL; ++q)
                #pragma unroll
                for (int j = 0; j < 4; ++j) acc[q][j] = 0.0f;
            #pragma unroll 16
            for (int e = 0; e < 16; ++e) {
                const int r = pk[e] >> 24;
                #pragma unroll
                for (int q = 0; q < NREL; ++q) {
                    const float sel = (r == q) ? 1.0f : 0.0f;
                    acc[q][0] += sel * xv[e].x;
                    acc[q][1] += sel * xv[e].y;
                    acc[q][2] += sel * xv[e].z;
                    acc[q][3] += sel * xv[e].w;
                }
            }
            for (int e = p0 + 16; e < p1; ++e) {   // rare: deg > 16
                const int s  = idx[e];
                const int tt = et[e];
                if (mask_used(um, mstride, s) && tt >= 0 && tt < NREL) {
                    const f32x4 w = *(const f32x4*)(x + (long)s * NCH + l * 4);
                    #pragma unroll
                    for (int q = 0; q < NREL; ++q) {
                        const float sel = (tt == q) ? 1.0f : 0.0f;
                        acc[q][0] += sel * w.x;
                        acc[q][1] += sel * w.y;
                        acc[q][2] += sel * w.z;
                        acc[q][3] += sel * w.w;
                    }
                }
            }
            // bf16 pack -> swizzled LDS A[hw][k], k = q*128 + 4l + j
            #pragma unroll
            for (int q = 0; q < NREL; ++q) {
                ushort4 pkv;
                pkv.x = f2bf(acc[q][0]); pkv.y = f2bf(acc[q][1]);
                pkv.z = f2bf(acc[q][2]); pkv.w = f2bf(acc[q][3]);
                const int eb   = (q * NCH + l * 4) * 2;
                const int addr = (hw * 2048 + eb) ^ ((hw & 7) << 4);
                *(ushort4*)(As + addr) = pkv;
            }
        }
        __syncthreads();

        // MFMA: 8 waves; wave wv covers output cols [wv*16, wv*16+16)
        const int wv   = t >> 6;
        const int lane = t & 63;
        const int row  = lane & 15;
        const int koff = (lane >> 4) * 8;
        const int col0 = wv * 16 + row;
        f32x4 c0 = {0.f, 0.f, 0.f, 0.f};
        #pragma unroll 8
        for (int kt = 0; kt < 32; ++kt) {
            const int aaddr = (row * 2048 + (kt * 32 + koff) * 2) ^ ((row & 7) << 4);
            const bf16x8 a  = *(const bf16x8*)(As + aaddr);
            const bf16x8 b0 = *(const bf16x8*)(Wb + ((kt * NCH + col0) << 5) + koff);
            c0 = __builtin_amdgcn_mfma_f32_16x16x32_bf16(a, b0, c0, 0, 0, 0);
        }

        // epilogue: stage scaled C in LDS, store contiguous 512B rows (nt)
        __syncthreads();
        float* Cs = (float*)As;            // reuse As as float Cs[16][128]
        {
            const int r4 = (lane >> 4) * 4;
            #pragma unroll
            for (int j = 0; j < 4; ++j) {
                const int rr = r4 + j;
                Cs[rr * NCH + col0] = c0[j] * invdeg[rr];
            }
        }
        __syncthreads();
        {
            const int nn = nidg[hw];
            if (nn >= 0) {
                const f32x4 vv = *(const f32x4*)(Cs + hw * NCH + l * 4);
                __builtin_nontemporal_store(vv,
                    (f32x4*)(out + (long)nn * NCH + l * 4));
            }
        }
        __syncthreads();                   // As reusable for next group
    }
}

extern "C" void kernel_launch(void* const* d_in, const int* in_sizes, int n_in,
                              void* d_out, int out_size, void* d_ws, size_t ws_size,
                              hipStream_t stream) {
    const float*         x   = (const float*)d_in[0];
    const float*         W   = (const float*)d_in[1];
    const float*         hb  = (const float*)d_in[2];
    const int*           ptr = (const int*)d_in[3];
    const int*           idx = (const int*)d_in[4];
    const int*           et  = (const int*)d_in[5];
    const unsigned char* um  = (const unsigned char*)d_in[6];
    const int*           hm  = (const int*)d_in[7];
    const int*           hs  = (const int*)d_in[8];
    float* out = (float*)d_out;

    const int num_node = in_sizes[7];           // history_map length

    // ws layout: cn (256B: [1]=mask width) | Wb
    int* cn = (int*)d_ws;
    unsigned short* Wb = (unsigned short*)((char*)d_ws + 256);

    const int nWin = (num_node + 63) / 64;      // 1024

    k_prep<<<512, 256, 0, stream>>>(W, Wb, cn, um);
    k_fused<<<nWin * 2, 512, 0, stream>>>(
        x, Wb, ptr, idx, et, um, cn, hb, hm, hs, out, num_node);
}

// Round 15
// 76.411 us; speedup vs baseline: 1.5474x; 1.5474x over previous
//
#include <hip/hip_runtime.h>
#include <hip/hip_bf16.h>
#include <stdint.h>

typedef __attribute__((ext_vector_type(4))) float f32x4;
typedef __attribute__((ext_vector_type(8))) short bf16x8;

#define NCH  128
#define NREL 8

__device__ __forceinline__ unsigned short f2bf(float f) {
    unsigned u = __builtin_bit_cast(unsigned, f);
    u += 0x7fffu + ((u >> 16) & 1u);          // RNE to bf16
    return (unsigned short)(u >> 16);
}

__device__ __forceinline__ bool mask_used(const unsigned char* um, int stride, int s) {
    if (stride == 1) return um[s] != 0;
    if (stride == 4) return ((const int*)um)[s] != 0;
    return ((const long long*)um)[s] != 0;
}

// ---------------------------------------------------------------------------
// K1 (512 blocks x 256): Wb convert (1 elem/thread). Blocks 0..255 also
// DETERMINISTICALLY classify: wave wv handles window w = b*4+wv (64 nodes),
// 64-lane ballot -> wlist[w*64..], wcnt[w]. No atomics, no tickets, no
// memset. Block 0 detects used_mask element width -> cn[1].
// ---------------------------------------------------------------------------
__global__ __launch_bounds__(256)
void k_prep(const float* __restrict__ W, unsigned short* __restrict__ Wb,
            int* __restrict__ cn, const unsigned char* __restrict__ um_raw,
            const int* __restrict__ hm, const int* __restrict__ hs,
            int* __restrict__ wlist, int* __restrict__ wcnt, int num_node) {
    const int t = threadIdx.x;
    const int b = blockIdx.x;
    const int o = b * 256 + t;
    {
        const int kk  = o & 31;
        const int col = (o >> 5) & (NCH - 1);
        const int kt  = o >> 12;
        Wb[o] = f2bf(W[(kt * 32 + kk) * NCH + col]);
    }
    if (b < 256) {                                 // classification role
        const int wv = t >> 6, l = t & 63;
        const int w  = b * 4 + wv;
        const int n  = w * 64 + l;
        bool nc = false;
        if (n < num_node) nc = !((hs[0] > 0) && (hm[n] != -1));
        const unsigned long long m = __ballot(nc);
        if (nc) wlist[w * 64 + __popcll(m & ((1ull << l) - 1))] = n;
        if (l == 0) wcnt[w] = __popcll(m);
    }
    if (b == 0) {                                  // mask width detect
        __shared__ unsigned sA, sB;
        if (t == 0) { sA = 0; sB = 0; }
        __syncthreads();
        unsigned a = 0, bb = 0;
        #pragma unroll 4
        for (int p = t; p < 1024; p += 256) {
            const unsigned v = um_raw[p];
            if ((p & 3) != 0) a |= v;   // bool kept 1B -> data off 4-align
            if ((p & 7) == 4) bb |= v;  // int32 -> data at 4 mod 8
        }
        if (a)  atomicOr(&sA, 1u);
        if (bb) atomicOr(&sB, 1u);
        __syncthreads();
        if (t == 0) cn[1] = sA ? 1 : (sB ? 4 : 8);
    }
}

// ---------------------------------------------------------------------------
// K2 (2048 blocks x 512): R12 grid ordering -- main role blocks [0,nWin)
// first, copy role blocks [nWin, 2*nWin) appended (contiguous ranges; NO
// parity role split -- R14 showed blockIdx&1 aliases roles onto XCD halves).
//   MAIN (window w): read wcnt/wlist, process groups of 16 non-cached nodes
//     through the proven pipeline (16 gathers in flight -> select-accumulate
//     -> swizzled LDS -> MFMA vs Wb -> LDS-staged 512B row stores).
//   COPY (window w): self-classify cached via ballot, 16 half-waves x 4
//     rounds copy history rows to out (nontemporal).
// ---------------------------------------------------------------------------
__global__ __launch_bounds__(512, 2)
void k_fused(const float* __restrict__ x, const unsigned short* __restrict__ Wb,
             const int* __restrict__ ptr, const int* __restrict__ idx,
             const int* __restrict__ et, const unsigned char* __restrict__ um,
             const int* __restrict__ cn, const int* __restrict__ wlist,
             const int* __restrict__ wcnt, const float* __restrict__ hb,
             const int* __restrict__ hm, const int* __restrict__ hs,
             float* __restrict__ out, int num_node, int nWin) {
    __shared__ __align__(16) char As[16 * NREL * NCH * 2];   // 32 KB, XOR-swizzled
    __shared__ int   lst[64];
    __shared__ int   cnt_s;
    __shared__ int   nidg[16];
    __shared__ float invdeg[16];

    const int t = threadIdx.x;
    const int hw    = t >> 5;       // half-wave id 0..15
    const int l     = t & 31;       // lane in half-wave; owns channels 4l..4l+3
    const int lbase = t & 32;       // half-wave base within its wave

    if ((int)blockIdx.x >= nWin) {                 // ---- copy role ----
        const int w = blockIdx.x - nWin;
        if (t < 64) {
            const int n = w * 64 + t;
            const bool cached = (n < num_node) && (hs[0] > 0) && (hm[n] != -1);
            const unsigned long long m = __ballot(cached);
            if (cached) lst[__popcll(m & ((1ull << t) - 1))] = n;
            if (t == 0) cnt_s = __popcll(m);
        }
        __syncthreads();
        const int nC = cnt_s;
        int   node[4];
        f32x4 v[4];
        #pragma unroll 4
        for (int j = 0; j < 4; ++j) {
            const int i = hw + j * 16;
            node[j] = (i < nC) ? lst[i] : -1;
            if (node[j] >= 0)
                v[j] = *(const f32x4*)(hb + (long)node[j] * NCH + l * 4);
        }
        #pragma unroll 4
        for (int j = 0; j < 4; ++j) {
            if (node[j] >= 0)
                __builtin_nontemporal_store(v[j],
                    (f32x4*)(out + (long)node[j] * NCH + l * 4));
        }
        return;
    }

    // ---- main role: window w = blockIdx.x ----
    const int w   = blockIdx.x;
    const int cnt = wcnt[w];
    if (cnt == 0) return;
    const int mstride = cn[1];
    const int nGroups = (cnt + 15) >> 4;
    for (int g = 0; g < nGroups; ++g) {
        if (t < 16) {
            const int i = g * 16 + t;
            nidg[t]   = (i < cnt) ? wlist[w * 64 + i] : -1;
            invdeg[t] = 0.0f;
        }
        __syncthreads();

        const int n = nidg[hw];
        if (n >= 0) {
            const int p0 = ptr[n], p1 = ptr[n + 1];
            const int deg = p1 - p0;
            if (l == 0) invdeg[hw] = (deg > 0) ? 1.0f / (float)deg : 0.0f;
            // lanes 0..15 of the half-wave fetch edge meta, pack (rel<<24)|src
            int myPk = NREL << 24;
            if (l < 16 && (p0 + l) < p1) {
                const int e  = p0 + l;
                const int s  = idx[e];
                const int tt = et[e];
                myPk = s | (((mask_used(um, mstride, s) && tt >= 0 && tt < NREL)
                             ? tt : NREL) << 24);
            }
            // all 16 row-gathers issued before any consumption
            int   pk[16];
            f32x4 xv[16];
            #pragma unroll 16
            for (int e = 0; e < 16; ++e) {
                pk[e] = __shfl(myPk, lbase + e, 64);
                xv[e] = *(const f32x4*)(x + (long)(pk[e] & 0xFFFFFF) * NCH + l * 4);
            }
            float acc[NREL][4];
            #pragma unroll
            for (int q = 0; q < NREL; ++q)
                #pragma unroll
                for (int j = 0; j < 4; ++j) acc[q][j] = 0.0f;
            #pragma unroll 16
            for (int e = 0; e < 16; ++e) {
                const int r = pk[e] >> 24;
                #pragma unroll
                for (int q = 0; q < NREL; ++q) {
                    const float sel = (r == q) ? 1.0f : 0.0f;
                    acc[q][0] += sel * xv[e].x;
                    acc[q][1] += sel * xv[e].y;
                    acc[q][2] += sel * xv[e].z;
                    acc[q][3] += sel * xv[e].w;
                }
            }
            for (int e = p0 + 16; e < p1; ++e) {   // rare: deg > 16
                const int s  = idx[e];
                const int tt = et[e];
                if (mask_used(um, mstride, s) && tt >= 0 && tt < NREL) {
                    const f32x4 wv = *(const f32x4*)(x + (long)s * NCH + l * 4);
                    #pragma unroll
                    for (int q = 0; q < NREL; ++q) {
                        const float sel = (tt == q) ? 1.0f : 0.0f;
                        acc[q][0] += sel * wv.x;
                        acc[q][1] += sel * wv.y;
                        acc[q][2] += sel * wv.z;
                        acc[q][3] += sel * wv.w;
                    }
                }
            }
            // bf16 pack -> swizzled LDS A[hw][k], k = q*128 + 4l + j
            #pragma unroll
            for (int q = 0; q < NREL; ++q) {
                ushort4 pkv;
                pkv.x = f2bf(acc[q][0]); pkv.y = f2bf(acc[q][1]);
                pkv.z = f2bf(acc[q][2]); pkv.w = f2bf(acc[q][3]);
                const int eb   = (q * NCH + l * 4) * 2;
                const int addr = (hw * 2048 + eb) ^ ((hw & 7) << 4);
                *(ushort4*)(As + addr) = pkv;
            }
        }
        __syncthreads();

        // MFMA: 8 waves; wave wv covers output cols [wv*16, wv*16+16)
        const int wv   = t >> 6;
        const int lane = t & 63;
        const int row  = lane & 15;
        const int koff = (lane >> 4) * 8;
        const int col0 = wv * 16 + row;
        f32x4 c0 = {0.f, 0.f, 0.f, 0.f};
        #pragma unroll 8
        for (int kt = 0; kt < 32; ++kt) {
            const int aaddr = (row * 2048 + (kt * 32 + koff) * 2) ^ ((row & 7) << 4);
            const bf16x8 a  = *(const bf16x8*)(As + aaddr);
            const bf16x8 b0 = *(const bf16x8*)(Wb + ((kt * NCH + col0) << 5) + koff);
            c0 = __builtin_amdgcn_mfma_f32_16x16x32_bf16(a, b0, c0, 0, 0, 0);
        }

        // epilogue: stage scaled C in LDS, store contiguous 512B rows (nt)
        __syncthreads();
        float* Cs = (float*)As;            // reuse As as float Cs[16][128]
        {
            const int r4 = (lane >> 4) * 4;
            #pragma unroll
            for (int j = 0; j < 4; ++j) {
                const int rr = r4 + j;
                Cs[rr * NCH + col0] = c0[j] * invdeg[rr];
            }
        }
        __syncthreads();
        {
            const int nn = nidg[hw];
            if (nn >= 0) {
                const f32x4 vv = *(const f32x4*)(Cs + hw * NCH + l * 4);
                __builtin_nontemporal_store(vv,
                    (f32x4*)(out + (long)nn * NCH + l * 4));
            }
        }
        __syncthreads();                   // As reusable for next group
    }
}

extern "C" void kernel_launch(void* const* d_in, const int* in_sizes, int n_in,
                              void* d_out, int out_size, void* d_ws, size_t ws_size,
                              hipStream_t stream) {
    const float*         x   = (const float*)d_in[0];
    const float*         W   = (const float*)d_in[1];
    const float*         hb  = (const float*)d_in[2];
    const int*           ptr = (const int*)d_in[3];
    const int*           idx = (const int*)d_in[4];
    const int*           et  = (const int*)d_in[5];
    const unsigned char* um  = (const unsigned char*)d_in[6];
    const int*           hm  = (const int*)d_in[7];
    const int*           hs  = (const int*)d_in[8];
    float* out = (float*)d_out;

    const int num_node = in_sizes[7];           // history_map length
    const int nWin     = (num_node + 63) / 64;  // 1024

    // ws layout: cn (256B: [1]=mask width) | wcnt | wlist | Wb
    size_t off = 256;
    int* cn    = (int*)d_ws;
    int* wcnt  = (int*)((char*)d_ws + off);     off += (((size_t)nWin * 4) + 255) & ~(size_t)255;
    int* wlist = (int*)((char*)d_ws + off);     off += (((size_t)nWin * 64 * 4) + 255) & ~(size_t)255;
    unsigned short* Wb = (unsigned short*)((char*)d_ws + off);

    k_prep<<<512, 256, 0, stream>>>(W, Wb, cn, um, hm, hs, wlist, wcnt, num_node);
    k_fused<<<nWin * 2, 512, 0, stream>>>(
        x, Wb, ptr, idx, et, um, cn, wlist, wcnt, hb, hm, hs, out, num_node, nWin);
}

// Round 16
// 44.311 us; speedup vs baseline: 2.6683x; 1.7244x over previous
//
#include <hip/hip_runtime.h>
#include <hip/hip_bf16.h>
#include <stdint.h>

typedef __attribute__((ext_vector_type(4))) float f32x4;
typedef __attribute__((ext_vector_type(8))) short bf16x8;

#define NCH  128
#define NREL 8
#define NSEG 32            // ticket counters / glist segments
#define SEGCAP 2048        // max nodes per segment (32 windows x 64)

__device__ __forceinline__ unsigned short f2bf(float f) {
    unsigned u = __builtin_bit_cast(unsigned, f);
    u += 0x7fffu + ((u >> 16) & 1u);          // RNE to bf16
    return (unsigned short)(u >> 16);
}

__device__ __forceinline__ bool mask_used(const unsigned char* um, int stride, int s) {
    if (stride == 1) return um[s] != 0;
    if (stride == 4) return ((const int*)um)[s] != 0;
    return ((const long long*)um)[s] != 0;
}

// ---------------------------------------------------------------------------
// R16 = R12 byte-for-byte (best measured: 44.9 us). R13/R14/R15 each changed
// the grid composition and regressed 30-70 us. Load-bearing details:
//  - memset + ticket-atomic classification in k_prep (blocks 0..255)
//  - k_fused: 4096 segmented main slots (683 packed 16-node groups + ~3400
//    fast-drain no-ops that let the scheduler reach copy blocks early)
//    followed by 1024 appended copy blocks -> cross-role CU overlap
//  - contiguous role ranges (parity split aliases roles onto XCD halves)
// ---------------------------------------------------------------------------
__global__ __launch_bounds__(256)
void k_prep(const float* __restrict__ W, unsigned short* __restrict__ Wb,
            int* __restrict__ cn, const unsigned char* __restrict__ um_raw,
            const int* __restrict__ hm, const int* __restrict__ hs,
            int* __restrict__ glist, int num_node) {
    const int t = threadIdx.x;
    const int b = blockIdx.x;
    const int o = b * 256 + t;
    if (o < NREL * NCH * NCH) {
        const int kk  = o & 31;
        const int col = (o >> 5) & (NCH - 1);
        const int kt  = o >> 12;
        Wb[o] = f2bf(W[(kt * 32 + kk) * NCH + col]);
    }
    if (b < 256) {                                 // classification role
        const int w = t >> 6, l = t & 63;
        const int n = b * 256 + w * 64 + l;
        bool nc = false;
        if (n < num_node) nc = !((hs[0] > 0) && (hm[n] != -1));
        const unsigned long long m = __ballot(nc);
        const int cnt = __popcll(m);
        const int seg = (b * 4 + w) & (NSEG - 1);
        int base = 0;
        if (l == 0 && cnt) base = atomicAdd(&cn[16 + seg * 16], cnt);
        base = __shfl(base, 0, 64);
        if (nc)
            glist[seg * SEGCAP + base + __popcll(m & ((1ull << l) - 1))] = n;
    }
    if (b == 0) {                                  // mask width detect
        __shared__ unsigned sA, sB;
        if (t == 0) { sA = 0; sB = 0; }
        __syncthreads();
        unsigned a = 0, bb = 0;
        #pragma unroll 4
        for (int p = t; p < 1024; p += 256) {
            const unsigned v = um_raw[p];
            if ((p & 3) != 0) a |= v;   // bool kept 1B -> data off 4-align
            if ((p & 7) == 4) bb |= v;  // int32 -> data at 4 mod 8
        }
        if (a)  atomicOr(&sA, 1u);
        if (bb) atomicOr(&sB, 1u);
        __syncthreads();
        if (t == 0) cn[1] = sA ? 1 : (sB ? 4 : 8);
    }
}

__global__ __launch_bounds__(512, 2)
void k_fused(const float* __restrict__ x, const unsigned short* __restrict__ Wb,
             const int* __restrict__ ptr, const int* __restrict__ idx,
             const int* __restrict__ et, const unsigned char* __restrict__ um,
             const int* __restrict__ cn, const int* __restrict__ glist,
             const float* __restrict__ hb, const int* __restrict__ hm,
             const int* __restrict__ hs, float* __restrict__ out,
             int num_node, int mainSlots) {
    __shared__ __align__(16) char As[16 * NREL * NCH * 2];   // 32 KB (main role)
    __shared__ int   nid[16];
    __shared__ float invdeg[16];
    __shared__ int   cList[64];
    __shared__ int   nC_s;

    const int t = threadIdx.x;

    if ((int)blockIdx.x >= mainSlots) {            // ---- copy role ----
        const int win = blockIdx.x - mainSlots;
        if (t < 64) {
            const int n = win * 64 + t;
            const bool cached = (n < num_node) && (hs[0] > 0) && (hm[n] != -1);
            const unsigned long long m = __ballot(cached);
            if (cached) cList[__popcll(m & ((1ull << t) - 1))] = n;
            if (t == 0) nC_s = __popcll(m);
        }
        __syncthreads();
        const int nC = nC_s;
        const int hw = t >> 5, l = t & 31;
        int   node[4];
        f32x4 v[4];
        #pragma unroll 4
        for (int j = 0; j < 4; ++j) {
            const int i = hw + j * 16;
            node[j] = (i < nC) ? cList[i] : -1;
            if (node[j] >= 0)
                v[j] = *(const f32x4*)(hb + (long)node[j] * NCH + l * 4);
        }
        #pragma unroll 4
        for (int j = 0; j < 4; ++j) {
            if (node[j] >= 0)
                __builtin_nontemporal_store(v[j],
                    (f32x4*)(out + (long)node[j] * NCH + l * 4));
        }
        return;
    }

    // ---- main role ----
    const int seg   = blockIdx.x & (NSEG - 1);
    const int grp   = blockIdx.x >> 5;
    const int cntS  = cn[16 + seg * 16];
    const int base  = grp * 16;
    if (base >= cntS) return;
    const int mstride = cn[1];
    if (t < 16) {
        const int i = base + t;
        nid[t]    = (i < cntS) ? glist[seg * SEGCAP + i] : -1;
        invdeg[t] = 0.0f;
    }
    __syncthreads();

    const int hw    = t >> 5;       // half-wave id 0..15 == node slot
    const int l     = t & 31;       // lane in half-wave; owns channels 4l..4l+3
    const int lbase = t & 32;       // half-wave base within its wave
    const int n     = nid[hw];

    if (n >= 0) {
        const int p0 = ptr[n], p1 = ptr[n + 1];
        const int deg = p1 - p0;
        if (l == 0) invdeg[hw] = (deg > 0) ? 1.0f / (float)deg : 0.0f;
        int myPk = NREL << 24;
        if (l < 16 && (p0 + l) < p1) {
            const int e  = p0 + l;
            const int s  = idx[e];
            const int tt = et[e];
            myPk = s | (((mask_used(um, mstride, s) && tt >= 0 && tt < NREL)
                         ? tt : NREL) << 24);
        }
        int   pk[16];
        f32x4 xv[16];
        #pragma unroll 16
        for (int e = 0; e < 16; ++e) {
            pk[e] = __shfl(myPk, lbase + e, 64);
            xv[e] = *(const f32x4*)(x + (long)(pk[e] & 0xFFFFFF) * NCH + l * 4);
        }
        float acc[NREL][4];
        #pragma unroll
        for (int q = 0; q < NREL; ++q)
            #pragma unroll
            for (int j = 0; j < 4; ++j) acc[q][j] = 0.0f;
        #pragma unroll 16
        for (int e = 0; e < 16; ++e) {
            const int r = pk[e] >> 24;
            #pragma unroll
            for (int q = 0; q < NREL; ++q) {
                const float sel = (r == q) ? 1.0f : 0.0f;
                acc[q][0] += sel * xv[e].x;
                acc[q][1] += sel * xv[e].y;
                acc[q][2] += sel * xv[e].z;
                acc[q][3] += sel * xv[e].w;
            }
        }
        for (int e = p0 + 16; e < p1; ++e) {       // rare: deg > 16
            const int s  = idx[e];
            const int tt = et[e];
            if (mask_used(um, mstride, s) && tt >= 0 && tt < NREL) {
                const f32x4 w = *(const f32x4*)(x + (long)s * NCH + l * 4);
                #pragma unroll
                for (int q = 0; q < NREL; ++q) {
                    const float sel = (tt == q) ? 1.0f : 0.0f;
                    acc[q][0] += sel * w.x;
                    acc[q][1] += sel * w.y;
                    acc[q][2] += sel * w.z;
                    acc[q][3] += sel * w.w;
                }
            }
        }
        #pragma unroll
        for (int q = 0; q < NREL; ++q) {
            ushort4 pkv;
            pkv.x = f2bf(acc[q][0]); pkv.y = f2bf(acc[q][1]);
            pkv.z = f2bf(acc[q][2]); pkv.w = f2bf(acc[q][3]);
            const int eb   = (q * NCH + l * 4) * 2;
            const int addr = (hw * 2048 + eb) ^ ((hw & 7) << 4);
            *(ushort4*)(As + addr) = pkv;
        }
    }
    __syncthreads();

    const int wv   = t >> 6;
    const int lane = t & 63;
    const int row  = lane & 15;
    const int koff = (lane >> 4) * 8;
    const int col0 = wv * 16 + row;
    f32x4 c0 = {0.f, 0.f, 0.f, 0.f};
    #pragma unroll 8
    for (int kt = 0; kt < 32; ++kt) {
        const int aaddr = (row * 2048 + (kt * 32 + koff) * 2) ^ ((row & 7) << 4);
        const bf16x8 a  = *(const bf16x8*)(As + aaddr);
        const bf16x8 b0 = *(const bf16x8*)(Wb + ((kt * NCH + col0) << 5) + koff);
        c0 = __builtin_amdgcn_mfma_f32_16x16x32_bf16(a, b0, c0, 0, 0, 0);
    }

    __syncthreads();
    float* Cs = (float*)As;                // reuse As as float Cs[16][128]
    {
        const int r4 = (lane >> 4) * 4;
        #pragma unroll
        for (int j = 0; j < 4; ++j) {
            const int rr = r4 + j;
            Cs[rr * NCH + col0] = c0[j] * invdeg[rr];
        }
    }
    __syncthreads();
    {
        const int nn = nid[hw];
        if (nn >= 0) {
            const f32x4 vv = *(const f32x4*)(Cs + hw * NCH + l * 4);
            __builtin_nontemporal_store(vv,
                (f32x4*)(out + (long)nn * NCH + l * 4));
        }
    }
}

extern "C" void kernel_launch(void* const* d_in, const int* in_sizes, int n_in,
                              void* d_out, int out_size, void* d_ws, size_t ws_size,
                              hipStream_t stream) {
    const float*         x   = (const float*)d_in[0];
    const float*         W   = (const float*)d_in[1];
    const float*         hb  = (const float*)d_in[2];
    const int*           ptr = (const int*)d_in[3];
    const int*           idx = (const int*)d_in[4];
    const int*           et  = (const int*)d_in[5];
    const unsigned char* um  = (const unsigned char*)d_in[6];
    const int*           hm  = (const int*)d_in[7];
    const int*           hs  = (const int*)d_in[8];
    float* out = (float*)d_out;

    const int num_node = in_sizes[7];           // history_map length

    // ws layout: cn (2560B: [1]=mask width, [16+c*16]=tickets) | glist 32seg | Wb
    size_t off = 2560;
    int* cn    = (int*)d_ws;
    int* glist = (int*)((char*)d_ws + off);       off += (size_t)NSEG * SEGCAP * 4;
    unsigned short* Wb = (unsigned short*)((char*)d_ws + off);

    const int mainSlots  = (num_node + 15) / 16;  // 4096
    const int copyBlocks = (num_node + 63) / 64;  // 1024

    hipMemsetAsync(cn, 0, 2560, stream);          // zero tickets each call
    k_prep<<<512, 256, 0, stream>>>(W, Wb, cn, um, hm, hs, glist, num_node);
    k_fused<<<mainSlots + copyBlocks, 512, 0, stream>>>(
        x, Wb, ptr, idx, et, um, cn, glist, hb, hm, hs, out, num_node, mainSlots);
}